// Round 1
// baseline (334.114 us; speedup 1.0000x reference)
//
#include <hip/hip_runtime.h>
#include <math.h>

typedef _Float16 f16_t;
typedef _Float16 f16x8 __attribute__((ext_vector_type(8)));
typedef _Float16 f16x4 __attribute__((ext_vector_type(4)));
typedef _Float16 f16x2 __attribute__((ext_vector_type(2)));
typedef __fp16 h16x2 __attribute__((ext_vector_type(2)));
typedef float f32x4 __attribute__((ext_vector_type(4)));

#define LDS_BYTES 103424

// fp32 -> fp16 weights into d_ws, k-chunk-major with 16B-group swizzle baked in.
// Chunk ck = [256 n][32 k] (8192 f16 = 16 KB). Element (n, k=ck*32+q*8+j) at
// chunkBase + n*32 + (q ^ ((n>>1)&3))*8 + j.  W1: chunks 0..3 at 0; W2: chunks 0..7 at 32768.
__global__ void wconv(const float* __restrict__ W1, const float* __restrict__ W2,
                      f16_t* __restrict__ o) {
  int i = blockIdx.x * 256 + threadIdx.x;  // 0..65535
  if (i < 32768) {
    int n = i >> 7, k = i & 127;
    int ck = k >> 5, q = (k >> 3) & 3, j = k & 7;
    o[ck * 8192 + n * 32 + (q ^ ((n >> 1) & 3)) * 8 + j] = (f16_t)W1[i];
  }
  {
    int n = i >> 8, k = i & 255;
    int ck = k >> 5, q = (k >> 3) & 3, j = k & 7;
    o[32768 + ck * 8192 + n * 32 + (q ^ ((n >> 1) & 3)) * 8 + j] = (f16_t)W2[i];
  }
}

__device__ __forceinline__ void stage16(const f16_t* g, f16_t* l) {
  __builtin_amdgcn_global_load_lds(
      (const __attribute__((address_space(1))) void*)g,
      (__attribute__((address_space(3))) void*)l, 16, 0, 0);
}

__device__ __forceinline__ f16x2 pk2(float a, float b) {
  union { h16x2 h; f16x2 f; } u;
  u.h = __builtin_amdgcn_cvt_pkrtz(a, b);
  return u.f;
}

#define COMP(v, r) ((r) == 0 ? (v).x : (r) == 1 ? (v).y : (r) == 2 ? (v).z : (v).w)

// Transposed fused MLP: D[feat][edge] = W @ x^T. Tile = 128 edges, 1024 threads,
// 16 waves as 4 feat-rows (64 feats) x 4 edge-cols (32 edges). acc[4][2] = 32 regs
// per wave (same per-wave shape as the 64-edge version; proven no-spill).
// Weights staged in 16 KB k-chunks through a 2x16KB ping-pong with ONE barrier per
// chunk. vs the 64-edge version: per-edge weight staging traffic AND barrier count
// halve; per-chunk stage per CU halves (1 block/CU instead of 2). LDS 103424 B ->
// 1 block/CU x 16 waves = same 16 waves/CU occupancy.
__global__ __launch_bounds__(1024) void fused_mlp(
    const float* __restrict__ h,
    const int* __restrict__ src,
    const int* __restrict__ dst,
    const f16_t* __restrict__ wks,
    const float* __restrict__ b1, const float* __restrict__ g1, const float* __restrict__ be1,
    const float* __restrict__ b2, const float* __restrict__ g2, const float* __restrict__ be2,
    const float* __restrict__ w3, const float* __restrict__ b3,
    float* __restrict__ out, int E, int nrows) {
  extern __shared__ __attribute__((aligned(16))) char smem[];
  f16_t* wlds = (f16_t*)smem;               // 2 x 8192 f16 ping-pong (32 KB)
  f16_t* xbuf = (f16_t*)(smem + 32768);     // x0 [128][128]; later x1 [128][256] (64 KB)
  float* ssum = (float*)(smem + 98304);     // [4 wf][128 e]
  float* ssq  = (float*)(smem + 100352);    // [4 wf][128 e]
  float* smean = (float*)(smem + 102400);   // [128]
  float* srstd = (float*)(smem + 102912);   // [128]

  const int t = threadIdx.x;
  const int ebase = blockIdx.x * 128;

  auto stage_chunk = [&](int dbuf, int off) {  // 16 KB chunk, 1024 thr x 16 B
    stage16(wks + off + t * 8, wlds + dbuf * 8192 + t * 8);
  };

  stage_chunk(0, 0);  // W1ck0 -> buf0, overlaps gather

  // ---------- gather: x0[m][k] = h[src][k]*h[dst][k], fp16, swizzled stride-128 ----------
  {
    const int m = t >> 3;   // edge 0..127
    const int j = t & 7;    // 16-float slice
    const int e = ebase + m;
    f16_t* xrow = xbuf + m * 128;
    const int g0 = ((j * 2) ^ m) & 15;
    const int g1i = ((j * 2 + 1) ^ m) & 15;
    if (e < E) {
      int si = src[e], di = dst[e];
      si = ((unsigned)si < (unsigned)nrows) ? si : 0;
      di = ((unsigned)di < (unsigned)nrows) ? di : 0;
      const float* hs = h + (long long)si * 128 + j * 16;
      const float* hd = h + (long long)di * 128 + j * 16;
      const float4 a0 = *(const float4*)(hs);
      const float4 a1 = *(const float4*)(hs + 4);
      const float4 a2 = *(const float4*)(hs + 8);
      const float4 a3 = *(const float4*)(hs + 12);
      const float4 c0 = *(const float4*)(hd);
      const float4 c1 = *(const float4*)(hd + 4);
      const float4 c2 = *(const float4*)(hd + 8);
      const float4 c3 = *(const float4*)(hd + 12);
      union { f16x8 v8; f16x2 v2[4]; } u0, u1;
      u0.v2[0] = pk2(a0.x * c0.x, a0.y * c0.y);
      u0.v2[1] = pk2(a0.z * c0.z, a0.w * c0.w);
      u0.v2[2] = pk2(a1.x * c1.x, a1.y * c1.y);
      u0.v2[3] = pk2(a1.z * c1.z, a1.w * c1.w);
      u1.v2[0] = pk2(a2.x * c2.x, a2.y * c2.y);
      u1.v2[1] = pk2(a2.z * c2.z, a2.w * c2.w);
      u1.v2[2] = pk2(a3.x * c3.x, a3.y * c3.y);
      u1.v2[3] = pk2(a3.z * c3.z, a3.w * c3.w);
      *(f16x8*)(xrow + g0 * 8) = u0.v8;
      *(f16x8*)(xrow + g1i * 8) = u1.v8;
    } else {
      f16x8 z = {};
      *(f16x8*)(xrow + g0 * 8) = z;
      *(f16x8*)(xrow + g1i * 8) = z;
    }
  }
  __syncthreads();  // b1: x0 + W1ck0 ready

  const int lane = t & 63;
  const int wave = t >> 6;   // 0..15
  const int wf = wave >> 2;  // 0..3: 64 feats
  const int we = wave & 3;   // 0..3: 32 edges
  const int c = lane & 15;
  const int q = lane >> 4;
  const int qp = q ^ ((c >> 1) & 3);  // weight-chunk swizzle (per-lane const)
  const int featBase = wf * 64;
  const int e0 = we * 32 + c, e1 = e0 + 16;
  const int woff = (featBase + c) * 32 + qp * 8;  // + msf*512, + buf*8192

  // ---------- GEMM1: K=128, 4 chunks, 1 barrier each ----------
  f32x4 acc[4][2];
#pragma unroll
  for (int msf = 0; msf < 4; ++msf)
#pragma unroll
    for (int n = 0; n < 2; ++n) acc[msf][n] = (f32x4){0.f, 0.f, 0.f, 0.f};

#pragma unroll
  for (int kc = 0; kc < 4; ++kc) {
    if (kc < 3) stage_chunk((kc + 1) & 1, (kc + 1) * 8192);  // W1ck(kc+1)
    else        stage_chunk(0, 32768);                        // W2ck0 (buf0 free since kc2)
    const int rb = (kc & 1) * 8192;
    const int gp = ((kc * 4 + q) ^ c) & 15;
    f16x8 af[4], bf[2];
#pragma unroll
    for (int msf = 0; msf < 4; ++msf)
      af[msf] = *(const f16x8*)(wlds + rb + woff + msf * 512);
    bf[0] = *(const f16x8*)(xbuf + e0 * 128 + gp * 8);
    bf[1] = *(const f16x8*)(xbuf + e1 * 128 + gp * 8);
#pragma unroll
    for (int msf = 0; msf < 4; ++msf)
#pragma unroll
      for (int n = 0; n < 2; ++n)
        acc[msf][n] = __builtin_amdgcn_mfma_f32_16x16x32_f16(af[msf], bf[n], acc[msf][n], 0, 0, 0);
    if (kc < 3) __syncthreads();  // b2..b4
  }

  // ---------- LN1 stats (dedicated region; concurrent with other waves' kc3) ----------
  {
    float s0 = 0.f, s1 = 0.f, q0 = 0.f, q1 = 0.f;
#pragma unroll
    for (int msf = 0; msf < 4; ++msf) {
      const float4 bv = *(const float4*)(b1 + featBase + msf * 16 + q * 4);
#pragma unroll
      for (int r = 0; r < 4; ++r) {
        const float b = COMP(bv, r);
        float v0 = acc[msf][0][r] + b, v1 = acc[msf][1][r] + b;
        acc[msf][0][r] = v0; acc[msf][1][r] = v1;
        s0 += v0; q0 += v0 * v0;
        s1 += v1; q1 += v1 * v1;
      }
    }
    s0 += __shfl_xor(s0, 16, 64); s0 += __shfl_xor(s0, 32, 64);
    q0 += __shfl_xor(q0, 16, 64); q0 += __shfl_xor(q0, 32, 64);
    s1 += __shfl_xor(s1, 16, 64); s1 += __shfl_xor(s1, 32, 64);
    q1 += __shfl_xor(q1, 16, 64); q1 += __shfl_xor(q1, 32, 64);
    if (q == 0) {
      ssum[wf * 128 + e0] = s0; ssq[wf * 128 + e0] = q0;
      ssum[wf * 128 + e1] = s1; ssq[wf * 128 + e1] = q1;
    }
  }
  __syncthreads();  // b5: stats ready; W2ck0 drained; all GEMM1 reads done
  stage_chunk(1, 32768 + 8192);  // W2ck1 -> buf1 (free since b5), drains at b6
  if (t < 128) {
    float s = ssum[t] + ssum[128 + t] + ssum[256 + t] + ssum[384 + t];
    float sq = ssq[t] + ssq[128 + t] + ssq[256 + t] + ssq[384 + t];
    float mu = s * (1.f / 256.f);
    float var = sq * (1.f / 256.f) - mu * mu;
    smean[t] = mu;
    srstd[t] = rsqrtf(var + 1e-5f);
  }
  __syncthreads();  // b6: mean/rstd ready; W2ck1 drained

  // ---------- LN1 normalize + ReLU -> x1 [128][256] (overwrites x0; x0 dead) ----------
  {
    const float rs0 = srstd[e0], nmr0 = -smean[e0] * rs0;
    const float rs1 = srstd[e1], nmr1 = -smean[e1] * rs1;
    const int j0 = (q & 1) * 4;
#pragma unroll
    for (int msf = 0; msf < 4; ++msf) {
      const float4 gv = *(const float4*)(g1 + featBase + msf * 16 + q * 4);
      const float4 bev = *(const float4*)(be1 + featBase + msf * 16 + q * 4);
      const int g = wf * 8 + msf * 2 + (q >> 1);  // feat 16B-group 0..31
      float v00, v01, v02, v03, v10, v11, v12, v13;
      v00 = fmaxf(fmaf(fmaf(acc[msf][0][0], rs0, nmr0), gv.x, bev.x), 0.f);
      v01 = fmaxf(fmaf(fmaf(acc[msf][0][1], rs0, nmr0), gv.y, bev.y), 0.f);
      v02 = fmaxf(fmaf(fmaf(acc[msf][0][2], rs0, nmr0), gv.z, bev.z), 0.f);
      v03 = fmaxf(fmaf(fmaf(acc[msf][0][3], rs0, nmr0), gv.w, bev.w), 0.f);
      v10 = fmaxf(fmaf(fmaf(acc[msf][1][0], rs1, nmr1), gv.x, bev.x), 0.f);
      v11 = fmaxf(fmaf(fmaf(acc[msf][1][1], rs1, nmr1), gv.y, bev.y), 0.f);
      v12 = fmaxf(fmaf(fmaf(acc[msf][1][2], rs1, nmr1), gv.z, bev.z), 0.f);
      v13 = fmaxf(fmaf(fmaf(acc[msf][1][3], rs1, nmr1), gv.w, bev.w), 0.f);
      union { f16x4 v4; f16x2 v2[2]; } h0, h1;
      h0.v2[0] = pk2(v00, v01); h0.v2[1] = pk2(v02, v03);
      h1.v2[0] = pk2(v10, v11); h1.v2[1] = pk2(v12, v13);
      const int gp0 = (g & 16) | ((g ^ e0) & 15);
      const int gp1 = (g & 16) | ((g ^ e1) & 15);
      *(f16x4*)(xbuf + e0 * 256 + gp0 * 8 + j0) = h0.v4;
      *(f16x4*)(xbuf + e1 * 256 + gp1 * 8 + j0) = h1.v4;
    }
  }
  __syncthreads();  // b7: x1 visible

  // ---------- GEMM2: K=256, 8 chunks (ck0,ck1 pre-staged), 1 barrier each ----------
  f32x4 acc2[4][2];
#pragma unroll
  for (int msf = 0; msf < 4; ++msf)
#pragma unroll
    for (int n = 0; n < 2; ++n) acc2[msf][n] = (f32x4){0.f, 0.f, 0.f, 0.f};

#pragma unroll
  for (int kc = 0; kc < 8; ++kc) {
    if (kc >= 1 && kc <= 6)
      stage_chunk((kc + 1) & 1, 32768 + (kc + 1) * 8192);  // W2ck(kc+1)
    const int rb = (kc & 1) * 8192;
    const int g = kc * 4 + q;  // 0..31
    const int gp0 = (g & 16) | ((g ^ e0) & 15);
    const int gp1 = (g & 16) | ((g ^ e1) & 15);
    f16x8 af[4], bf[2];
#pragma unroll
    for (int msf = 0; msf < 4; ++msf)
      af[msf] = *(const f16x8*)(wlds + rb + woff + msf * 512);
    bf[0] = *(const f16x8*)(xbuf + e0 * 256 + gp0 * 8);
    bf[1] = *(const f16x8*)(xbuf + e1 * 256 + gp1 * 8);
#pragma unroll
    for (int msf = 0; msf < 4; ++msf)
#pragma unroll
      for (int n = 0; n < 2; ++n)
        acc2[msf][n] = __builtin_amdgcn_mfma_f32_16x16x32_f16(af[msf], bf[n], acc2[msf][n], 0, 0, 0);
    if (kc < 7) __syncthreads();  // b8..b14
  }

  // ---------- LN2 stats ----------
  {
    float s0 = 0.f, s1 = 0.f, q0 = 0.f, q1 = 0.f;
#pragma unroll
    for (int msf = 0; msf < 4; ++msf) {
      const float4 bv = *(const float4*)(b2 + featBase + msf * 16 + q * 4);
#pragma unroll
      for (int r = 0; r < 4; ++r) {
        const float b = COMP(bv, r);
        float v0 = acc2[msf][0][r] + b, v1 = acc2[msf][1][r] + b;
        acc2[msf][0][r] = v0; acc2[msf][1][r] = v1;
        s0 += v0; q0 += v0 * v0;
        s1 += v1; q1 += v1 * v1;
      }
    }
    s0 += __shfl_xor(s0, 16, 64); s0 += __shfl_xor(s0, 32, 64);
    q0 += __shfl_xor(q0, 16, 64); q0 += __shfl_xor(q0, 32, 64);
    s1 += __shfl_xor(s1, 16, 64); s1 += __shfl_xor(s1, 32, 64);
    q1 += __shfl_xor(q1, 16, 64); q1 += __shfl_xor(q1, 32, 64);
    if (q == 0) {
      ssum[wf * 128 + e0] = s0; ssq[wf * 128 + e0] = q0;
      ssum[wf * 128 + e1] = s1; ssq[wf * 128 + e1] = q1;
    }
  }
  __syncthreads();  // b15
  if (t < 128) {
    float s = ssum[t] + ssum[128 + t] + ssum[256 + t] + ssum[384 + t];
    float sq = ssq[t] + ssq[128 + t] + ssq[256 + t] + ssq[384 + t];
    float mu = s * (1.f / 256.f);
    float var = sq * (1.f / 256.f) - mu * mu;
    smean[t] = mu;
    srstd[t] = rsqrtf(var + 1e-5f);
  }
  __syncthreads();  // b16

  // ---------- LN2 normalize + ReLU + dot(W3) + sigmoid ----------
  {
    const float rs0 = srstd[e0], nmr0 = -smean[e0] * rs0;
    const float rs1 = srstd[e1], nmr1 = -smean[e1] * rs1;
    float p0 = 0.f, p1 = 0.f;
#pragma unroll
    for (int msf = 0; msf < 4; ++msf) {
      const float4 gv = *(const float4*)(g2 + featBase + msf * 16 + q * 4);
      const float4 bev = *(const float4*)(be2 + featBase + msf * 16 + q * 4);
      const float4 wv = *(const float4*)(w3 + featBase + msf * 16 + q * 4);
#pragma unroll
      for (int r = 0; r < 4; ++r) {
        const float gr = COMP(gv, r), ber = COMP(bev, r), wr = COMP(wv, r);
        float v0 = fmaxf(fmaf(fmaf(acc2[msf][0][r], rs0, nmr0), gr, ber), 0.f);
        float v1 = fmaxf(fmaf(fmaf(acc2[msf][1][r], rs1, nmr1), gr, ber), 0.f);
        p0 = fmaf(v0, wr, p0);
        p1 = fmaf(v1, wr, p1);
      }
    }
    p0 += __shfl_xor(p0, 16, 64); p0 += __shfl_xor(p0, 32, 64);
    p1 += __shfl_xor(p1, 16, 64); p1 += __shfl_xor(p1, 32, 64);
    if (q == 0) {
      ssum[wf * 128 + e0] = p0;  // old ssum dead after b16 reduce
      ssum[wf * 128 + e1] = p1;
    }
  }
  __syncthreads();  // b17
  if (t < 128) {
    int e = ebase + t;
    if (e < E) {
      float sres = ssum[t] + ssum[128 + t] + ssum[256 + t] + ssum[384 + t] + b3[0];
      out[e] = 1.f / (1.f + __expf(-sres));
    }
  }
}

extern "C" void kernel_launch(void* const* d_in, const int* in_sizes, int n_in,
                              void* d_out, int out_size, void* d_ws, size_t ws_size,
                              hipStream_t stream) {
  const float* h = (const float*)d_in[0];
  const int* src = (const int*)d_in[1];
  const int* dst = (const int*)d_in[2];
  const float* W1 = (const float*)d_in[3];
  const float* b1 = (const float*)d_in[4];
  const float* g1 = (const float*)d_in[5];
  const float* be1 = (const float*)d_in[6];
  const float* W2 = (const float*)d_in[7];
  const float* b2 = (const float*)d_in[8];
  const float* g2 = (const float*)d_in[9];
  const float* be2 = (const float*)d_in[10];
  const float* W3 = (const float*)d_in[11];
  const float* b3 = (const float*)d_in[12];
  float* out = (float*)d_out;
  const int E = in_sizes[1];
  const int nrows = in_sizes[0] / 128;
  f16_t* wks = (f16_t*)d_ws;  // 98304 f16 = 196608 bytes

  wconv<<<256, 256, 0, stream>>>(W1, W2, wks);
  (void)hipFuncSetAttribute((const void*)fused_mlp,
                            hipFuncAttributeMaxDynamicSharedMemorySize, LDS_BYTES);
  const int tiles = (E + 127) / 128;
  fused_mlp<<<tiles, 1024, LDS_BYTES, stream>>>(h, src, dst, wks, b1, g1, be1,
                                                b2, g2, be2, W3, b3, out, E, nrows);
}

// Round 2
// 300.869 us; speedup vs baseline: 1.1105x; 1.1105x over previous
//
#include <hip/hip_runtime.h>
#include <math.h>

typedef _Float16 f16_t;
typedef _Float16 f16x8 __attribute__((ext_vector_type(8)));
typedef _Float16 f16x4 __attribute__((ext_vector_type(4)));
typedef _Float16 f16x2 __attribute__((ext_vector_type(2)));
typedef __fp16 h16x2 __attribute__((ext_vector_type(2)));
typedef float f32x4 __attribute__((ext_vector_type(4)));

#define LDS_BYTES 81920

// fp32 -> fp16 weights into d_ws, k-chunk-major with 16B-group swizzle baked in.
// Chunk ck = [256 n][32 k] (8192 f16 = 16 KB). Element (n, k=ck*32+q*8+j) at
// chunkBase + n*32 + (q ^ ((n>>1)&3))*8 + j.  Global chunk j=0..11: W1 ck0..3 at
// j*8192 (j=0..3), W2 ck0..7 at j*8192 (j=4..11) -- contiguous stream.
__global__ void wconv(const float* __restrict__ W1, const float* __restrict__ W2,
                      f16_t* __restrict__ o) {
  int i = blockIdx.x * 256 + threadIdx.x;  // 0..65535
  if (i < 32768) {
    int n = i >> 7, k = i & 127;
    int ck = k >> 5, q = (k >> 3) & 3, j = k & 7;
    o[ck * 8192 + n * 32 + (q ^ ((n >> 1) & 3)) * 8 + j] = (f16_t)W1[i];
  }
  {
    int n = i >> 8, k = i & 255;
    int ck = k >> 5, q = (k >> 3) & 3, j = k & 7;
    o[32768 + ck * 8192 + n * 32 + (q ^ ((n >> 1) & 3)) * 8 + j] = (f16_t)W2[i];
  }
}

__device__ __forceinline__ void stage16(const f16_t* g, f16_t* l) {
  __builtin_amdgcn_global_load_lds(
      (const __attribute__((address_space(1))) void*)g,
      (__attribute__((address_space(3))) void*)l, 16, 0, 0);
}

__device__ __forceinline__ f16x2 pk2(float a, float b) {
  union { h16x2 h; f16x2 f; } u;
  u.h = __builtin_amdgcn_cvt_pkrtz(a, b);
  return u.f;
}

#define COMP(v, r) ((r) == 0 ? (v).x : (r) == 1 ? (v).y : (r) == 2 ? (v).z : (v).w)

// Counted-vmcnt barriers (T4): wait only for the chunk about to be consumed,
// leaving the newest prefetch in flight ACROSS the barrier. "memory" clobber
// pins LDS/VMEM ops on the correct side.
#define WAITBAR2() do { \
    asm volatile("s_waitcnt vmcnt(2) lgkmcnt(0)" ::: "memory"); \
    __builtin_amdgcn_s_barrier(); } while (0)
#define WAITBAR0() do { \
    asm volatile("s_waitcnt vmcnt(0) lgkmcnt(0)" ::: "memory"); \
    __builtin_amdgcn_s_barrier(); } while (0)
#define LGKMBAR() do { \
    asm volatile("s_waitcnt lgkmcnt(0)" ::: "memory"); \
    __builtin_amdgcn_s_barrier(); } while (0)

// Transposed fused MLP: D[feat][edge] = W @ x^T. Tile = 64 edges, 512 threads,
// 8 waves as 4 feat-rows (64 feats) x 2 edge-cols (32 edges). acc[4][2] = 32 regs.
// Weights stream through a 3x16KB ring with PREFETCH DEPTH 2: per iter j --
// {waitcnt vmcnt(2); s_barrier; stage(j+2)->slot (j+2)%3; compute chunk j from
// slot j%3}. Each stage gets two compute phases to land instead of one, so the
// per-chunk vmcnt drain stall of the __syncthreads version vanishes. WAR safe:
// the slot being staged was last read two barriers ago. RAW safe: every wave
// waits vmcnt before the barrier, so after the barrier ALL waves' portions of
// the consumed chunk have landed.
// LDS = 48K ring + 32K xbuf = 81920 B exactly -> 2 blocks/CU (163840 = 160 KiB),
// preserving the two independent barrier domains that round-1 proved essential.
// LN stats: no smean/srstd arrays -- each lane reads the 4 wf-partials for its
// own e0/e1 (two float4s) and computes mu/rstd redundantly. LN1 stats live in
// the dead second half of xbuf; LN2 stats + final p-partials in ring slot 0
// (dead after chunk 9's last read at iter 9).
__global__ __launch_bounds__(512) void fused_mlp(
    const float* __restrict__ h,
    const int* __restrict__ src,
    const int* __restrict__ dst,
    const f16_t* __restrict__ wks,
    const float* __restrict__ b1, const float* __restrict__ g1, const float* __restrict__ be1,
    const float* __restrict__ b2, const float* __restrict__ g2, const float* __restrict__ be2,
    const float* __restrict__ w3, const float* __restrict__ b3,
    float* __restrict__ out, int E, int nrows) {
  extern __shared__ __attribute__((aligned(16))) char smem[];
  f16_t* wlds = (f16_t*)smem;               // 3 x 8192 f16 ring (48 KB)
  f16_t* xbuf = (f16_t*)(smem + 49152);     // x0 [64][128]; later x1 [64][256] (32 KB)
  float* sst1 = (float*)(smem + 65536);     // LN1 stats [64 e][8] in x0-dead half of xbuf
  float* sst2 = (float*)smem;               // LN2 stats + p [64 e][8] in ring slot 0

  const int t = threadIdx.x;
  const int ebase = blockIdx.x * 64;

  auto stage_chunk = [&](int slot, int off) {  // 16 KB chunk, 512 thr x 16 B x 2
    const f16_t* g0 = wks + off + t * 8;
    f16_t* l0 = wlds + slot * 8192 + t * 8;
    stage16(g0, l0);
    stage16(g0 + 4096, l0 + 4096);
  };

  stage_chunk(0, 0);      // chunk 0 (W1ck0)
  stage_chunk(1, 8192);   // chunk 1 (W1ck1)

  // ---------- gather: x0[m][k] = h[src][k]*h[dst][k], fp16, swizzled stride-128 ----------
  {
    const int m = t >> 3;   // edge 0..63
    const int j = t & 7;    // 16-float slice
    const int e = ebase + m;
    f16_t* xrow = xbuf + m * 128;
    const int g0 = ((j * 2) ^ m) & 15;
    const int g1i = ((j * 2 + 1) ^ m) & 15;
    if (e < E) {
      int si = src[e], di = dst[e];
      si = ((unsigned)si < (unsigned)nrows) ? si : 0;
      di = ((unsigned)di < (unsigned)nrows) ? di : 0;
      const float* hs = h + (long long)si * 128 + j * 16;
      const float* hd = h + (long long)di * 128 + j * 16;
      const float4 a0 = *(const float4*)(hs);
      const float4 a1 = *(const float4*)(hs + 4);
      const float4 a2 = *(const float4*)(hs + 8);
      const float4 a3 = *(const float4*)(hs + 12);
      const float4 c0 = *(const float4*)(hd);
      const float4 c1 = *(const float4*)(hd + 4);
      const float4 c2 = *(const float4*)(hd + 8);
      const float4 c3 = *(const float4*)(hd + 12);
      union { f16x8 v8; f16x2 v2[4]; } u0, u1;
      u0.v2[0] = pk2(a0.x * c0.x, a0.y * c0.y);
      u0.v2[1] = pk2(a0.z * c0.z, a0.w * c0.w);
      u0.v2[2] = pk2(a1.x * c1.x, a1.y * c1.y);
      u0.v2[3] = pk2(a1.z * c1.z, a1.w * c1.w);
      u1.v2[0] = pk2(a2.x * c2.x, a2.y * c2.y);
      u1.v2[1] = pk2(a2.z * c2.z, a2.w * c2.w);
      u1.v2[2] = pk2(a3.x * c3.x, a3.y * c3.y);
      u1.v2[3] = pk2(a3.z * c3.z, a3.w * c3.w);
      *(f16x8*)(xrow + g0 * 8) = u0.v8;
      *(f16x8*)(xrow + g1i * 8) = u1.v8;
    } else {
      f16x8 z = {};
      *(f16x8*)(xrow + g0 * 8) = z;
      *(f16x8*)(xrow + g1i * 8) = z;
    }
  }
  // NOTE: gather's own VMEM loads drain the prologue stages implicitly (in-order
  // vmcnt); iter-0's WAITBAR provides the barrier + lgkm drain for x0.

  const int lane = t & 63;
  const int wave = t >> 6;
  const int wf = wave >> 1;  // 0..3: 64 feats
  const int we = wave & 1;   // 0..1: 32 edges
  const int c = lane & 15;
  const int q = lane >> 4;
  const int qp = q ^ ((c >> 1) & 3);  // weight-chunk swizzle (per-lane const)
  const int featBase = wf * 64;
  const int e0 = we * 32 + c, e1 = e0 + 16;
  const int woff = (featBase + c) * 32 + qp * 8;  // + msf*512, + slot*8192

  // ---------- GEMM1: K=128, global chunks 0..3 ----------
  f32x4 acc[4][2];
#pragma unroll
  for (int msf = 0; msf < 4; ++msf)
#pragma unroll
    for (int n = 0; n < 2; ++n) acc[msf][n] = (f32x4){0.f, 0.f, 0.f, 0.f};

#pragma unroll
  for (int j = 0; j < 4; ++j) {
    WAITBAR2();                                   // chunk j landed everywhere
    stage_chunk((j + 2) % 3, (j + 2) * 8192);     // prefetch chunk j+2
    const int rb = (j % 3) * 8192;
    const int gp = ((j * 4 + q) ^ c) & 15;
    f16x8 af[4], bf[2];
#pragma unroll
    for (int msf = 0; msf < 4; ++msf)
      af[msf] = *(const f16x8*)(wlds + rb + woff + msf * 512);
    bf[0] = *(const f16x8*)(xbuf + e0 * 128 + gp * 8);
    bf[1] = *(const f16x8*)(xbuf + e1 * 128 + gp * 8);
#pragma unroll
    for (int msf = 0; msf < 4; ++msf)
#pragma unroll
      for (int n = 0; n < 2; ++n)
        acc[msf][n] = __builtin_amdgcn_mfma_f32_16x16x32_f16(af[msf], bf[n], acc[msf][n], 0, 0, 0);
  }

  // ---------- LN1 stats (concurrent with other waves' chunk-3 compute) ----------
  {
    float s0 = 0.f, s1 = 0.f, q0 = 0.f, q1 = 0.f;
#pragma unroll
    for (int msf = 0; msf < 4; ++msf) {
      const float4 bv = *(const float4*)(b1 + featBase + msf * 16 + q * 4);
#pragma unroll
      for (int r = 0; r < 4; ++r) {
        const float b = COMP(bv, r);
        float v0 = acc[msf][0][r] + b, v1 = acc[msf][1][r] + b;
        acc[msf][0][r] = v0; acc[msf][1][r] = v1;
        s0 += v0; q0 += v0 * v0;
        s1 += v1; q1 += v1 * v1;
      }
    }
    s0 += __shfl_xor(s0, 16, 64); s0 += __shfl_xor(s0, 32, 64);
    q0 += __shfl_xor(q0, 16, 64); q0 += __shfl_xor(q0, 32, 64);
    s1 += __shfl_xor(s1, 16, 64); s1 += __shfl_xor(s1, 32, 64);
    q1 += __shfl_xor(q1, 16, 64); q1 += __shfl_xor(q1, 32, 64);
    if (q == 0) {
      sst1[e0 * 8 + wf] = s0; sst1[e0 * 8 + 4 + wf] = q0;
      sst1[e1 * 8 + wf] = s1; sst1[e1 * 8 + 4 + wf] = q1;
    }
  }
  LGKMBAR();  // b5: stats visible (chunks 4,5 remain in flight)

  // Per-lane redundant mean/rstd: read 4 partials for own e0/e1, no smean array.
  float mu0, rs0, mu1, rs1;
  {
    const float4 sa = *(const float4*)(sst1 + e0 * 8);
    const float4 qa = *(const float4*)(sst1 + e0 * 8 + 4);
    const float4 sb = *(const float4*)(sst1 + e1 * 8);
    const float4 qb = *(const float4*)(sst1 + e1 * 8 + 4);
    LGKMBAR();  // b6: all stat reads in regs before x1 overwrites this region
    mu0 = (sa.x + sa.y + sa.z + sa.w) * (1.f / 256.f);
    float var0 = (qa.x + qa.y + qa.z + qa.w) * (1.f / 256.f) - mu0 * mu0;
    rs0 = rsqrtf(var0 + 1e-5f);
    mu1 = (sb.x + sb.y + sb.z + sb.w) * (1.f / 256.f);
    float var1 = (qb.x + qb.y + qb.z + qb.w) * (1.f / 256.f) - mu1 * mu1;
    rs1 = rsqrtf(var1 + 1e-5f);
  }

  // ---------- LN1 normalize + ReLU -> x1 [64][256] (overwrites x0 + sst1) ----------
  {
    const float nmr0 = -mu0 * rs0;
    const float nmr1 = -mu1 * rs1;
    const int j0 = (q & 1) * 4;
#pragma unroll
    for (int msf = 0; msf < 4; ++msf) {
      const float4 gv = *(const float4*)(g1 + featBase + msf * 16 + q * 4);
      const float4 bev = *(const float4*)(be1 + featBase + msf * 16 + q * 4);
      const int g = wf * 8 + msf * 2 + (q >> 1);  // feat 16B-group 0..31
      float v00, v01, v02, v03, v10, v11, v12, v13;
      v00 = fmaxf(fmaf(fmaf(acc[msf][0][0], rs0, nmr0), gv.x, bev.x), 0.f);
      v01 = fmaxf(fmaf(fmaf(acc[msf][0][1], rs0, nmr0), gv.y, bev.y), 0.f);
      v02 = fmaxf(fmaf(fmaf(acc[msf][0][2], rs0, nmr0), gv.z, bev.z), 0.f);
      v03 = fmaxf(fmaf(fmaf(acc[msf][0][3], rs0, nmr0), gv.w, bev.w), 0.f);
      v10 = fmaxf(fmaf(fmaf(acc[msf][1][0], rs1, nmr1), gv.x, bev.x), 0.f);
      v11 = fmaxf(fmaf(fmaf(acc[msf][1][1], rs1, nmr1), gv.y, bev.y), 0.f);
      v12 = fmaxf(fmaf(fmaf(acc[msf][1][2], rs1, nmr1), gv.z, bev.z), 0.f);
      v13 = fmaxf(fmaf(fmaf(acc[msf][1][3], rs1, nmr1), gv.w, bev.w), 0.f);
      union { f16x4 v4; f16x2 v2[2]; } h0, h1;
      h0.v2[0] = pk2(v00, v01); h0.v2[1] = pk2(v02, v03);
      h1.v2[0] = pk2(v10, v11); h1.v2[1] = pk2(v12, v13);
      const int gp0 = (g & 16) | ((g ^ e0) & 15);
      const int gp1 = (g & 16) | ((g ^ e1) & 15);
      *(f16x4*)(xbuf + e0 * 256 + gp0 * 8 + j0) = h0.v4;
      *(f16x4*)(xbuf + e1 * 256 + gp1 * 8 + j0) = h1.v4;
    }
  }

  // ---------- GEMM2: K=256, global chunks 4..11 ----------
  f32x4 acc2[4][2];
#pragma unroll
  for (int msf = 0; msf < 4; ++msf)
#pragma unroll
    for (int n = 0; n < 2; ++n) acc2[msf][n] = (f32x4){0.f, 0.f, 0.f, 0.f};

#pragma unroll
  for (int j = 4; j < 12; ++j) {
    if (j == 11) WAITBAR0(); else WAITBAR2();     // chunk j landed; x1 visible (j==4)
    if (j <= 9) stage_chunk((j + 2) % 3, (j + 2) * 8192);
    const int rb = (j % 3) * 8192;
    const int g = (j - 4) * 4 + q;  // 0..31
    const int gp0 = (g & 16) | ((g ^ e0) & 15);
    const int gp1 = (g & 16) | ((g ^ e1) & 15);
    f16x8 af[4], bf[2];
#pragma unroll
    for (int msf = 0; msf < 4; ++msf)
      af[msf] = *(const f16x8*)(wlds + rb + woff + msf * 512);
    bf[0] = *(const f16x8*)(xbuf + e0 * 256 + gp0 * 8);
    bf[1] = *(const f16x8*)(xbuf + e1 * 256 + gp1 * 8);
#pragma unroll
    for (int msf = 0; msf < 4; ++msf)
#pragma unroll
      for (int n = 0; n < 2; ++n)
        acc2[msf][n] = __builtin_amdgcn_mfma_f32_16x16x32_f16(af[msf], bf[n], acc2[msf][n], 0, 0, 0);
  }

  // ---------- LN2 stats (ring slot 0 is dead: last read iter 9, last stage drained) ----------
  {
    float s0 = 0.f, s1 = 0.f, q0 = 0.f, q1 = 0.f;
#pragma unroll
    for (int msf = 0; msf < 4; ++msf) {
      const float4 bv = *(const float4*)(b2 + featBase + msf * 16 + q * 4);
#pragma unroll
      for (int r = 0; r < 4; ++r) {
        const float b = COMP(bv, r);
        float v0 = acc2[msf][0][r] + b, v1 = acc2[msf][1][r] + b;
        acc2[msf][0][r] = v0; acc2[msf][1][r] = v1;
        s0 += v0; q0 += v0 * v0;
        s1 += v1; q1 += v1 * v1;
      }
    }
    s0 += __shfl_xor(s0, 16, 64); s0 += __shfl_xor(s0, 32, 64);
    q0 += __shfl_xor(q0, 16, 64); q0 += __shfl_xor(q0, 32, 64);
    s1 += __shfl_xor(s1, 16, 64); s1 += __shfl_xor(s1, 32, 64);
    q1 += __shfl_xor(q1, 16, 64); q1 += __shfl_xor(q1, 32, 64);
    if (q == 0) {
      sst2[e0 * 8 + wf] = s0; sst2[e0 * 8 + 4 + wf] = q0;
      sst2[e1 * 8 + wf] = s1; sst2[e1 * 8 + 4 + wf] = q1;
    }
  }
  LGKMBAR();  // b15

  {
    const float4 sa = *(const float4*)(sst2 + e0 * 8);
    const float4 qa = *(const float4*)(sst2 + e0 * 8 + 4);
    const float4 sb = *(const float4*)(sst2 + e1 * 8);
    const float4 qb = *(const float4*)(sst2 + e1 * 8 + 4);
    LGKMBAR();  // b16: partial reads done before p overwrites sst2
    mu0 = (sa.x + sa.y + sa.z + sa.w) * (1.f / 256.f);
    float var0 = (qa.x + qa.y + qa.z + qa.w) * (1.f / 256.f) - mu0 * mu0;
    rs0 = rsqrtf(var0 + 1e-5f);
    mu1 = (sb.x + sb.y + sb.z + sb.w) * (1.f / 256.f);
    float var1 = (qb.x + qb.y + qb.z + qb.w) * (1.f / 256.f) - mu1 * mu1;
    rs1 = rsqrtf(var1 + 1e-5f);
  }

  // ---------- LN2 normalize + ReLU + dot(W3) + sigmoid ----------
  {
    const float nmr0 = -mu0 * rs0;
    const float nmr1 = -mu1 * rs1;
    float p0 = 0.f, p1 = 0.f;
#pragma unroll
    for (int msf = 0; msf < 4; ++msf) {
      const float4 gv = *(const float4*)(g2 + featBase + msf * 16 + q * 4);
      const float4 bev = *(const float4*)(be2 + featBase + msf * 16 + q * 4);
      const float4 wv = *(const float4*)(w3 + featBase + msf * 16 + q * 4);
#pragma unroll
      for (int r = 0; r < 4; ++r) {
        const float gr = COMP(gv, r), ber = COMP(bev, r), wr = COMP(wv, r);
        float v0 = fmaxf(fmaf(fmaf(acc2[msf][0][r], rs0, nmr0), gr, ber), 0.f);
        float v1 = fmaxf(fmaf(fmaf(acc2[msf][1][r], rs1, nmr1), gr, ber), 0.f);
        p0 = fmaf(v0, wr, p0);
        p1 = fmaf(v1, wr, p1);
      }
    }
    p0 += __shfl_xor(p0, 16, 64); p0 += __shfl_xor(p0, 32, 64);
    p1 += __shfl_xor(p1, 16, 64); p1 += __shfl_xor(p1, 32, 64);
    if (q == 0) {
      sst2[e0 * 8 + wf] = p0;
      sst2[e1 * 8 + wf] = p1;
    }
  }
  LGKMBAR();  // b17
  if (t < 64) {
    int e = ebase + t;
    if (e < E) {
      const float4 pv = *(const float4*)(sst2 + t * 8);
      float sres = pv.x + pv.y + pv.z + pv.w + b3[0];
      out[e] = 1.f / (1.f + __expf(-sres));
    }
  }
}

extern "C" void kernel_launch(void* const* d_in, const int* in_sizes, int n_in,
                              void* d_out, int out_size, void* d_ws, size_t ws_size,
                              hipStream_t stream) {
  const float* h = (const float*)d_in[0];
  const int* src = (const int*)d_in[1];
  const int* dst = (const int*)d_in[2];
  const float* W1 = (const float*)d_in[3];
  const float* b1 = (const float*)d_in[4];
  const float* g1 = (const float*)d_in[5];
  const float* be1 = (const float*)d_in[6];
  const float* W2 = (const float*)d_in[7];
  const float* b2 = (const float*)d_in[8];
  const float* g2 = (const float*)d_in[9];
  const float* be2 = (const float*)d_in[10];
  const float* W3 = (const float*)d_in[11];
  const float* b3 = (const float*)d_in[12];
  float* out = (float*)d_out;
  const int E = in_sizes[1];
  const int nrows = in_sizes[0] / 128;
  f16_t* wks = (f16_t*)d_ws;  // 98304 f16 = 196608 bytes

  wconv<<<256, 256, 0, stream>>>(W1, W2, wks);
  (void)hipFuncSetAttribute((const void*)fused_mlp,
                            hipFuncAttributeMaxDynamicSharedMemorySize, LDS_BYTES);
  const int tiles = (E + 63) / 64;
  fused_mlp<<<tiles, 512, LDS_BYTES, stream>>>(h, src, dst, wks, b1, g1, be1,
                                               b2, g2, be2, W3, b3, out, E, nrows);
}